// Round 11
// baseline (63.976 us; speedup 1.0000x reference)
//
#include <hip/hip_runtime.h>
#include <hip/hip_bf16.h>
#include <math.h>

#define KBINS 5
#define NF 4
#define BV 3.0f

typedef float f32x4 __attribute__((ext_vector_type(4)));

// ws float layout (per flow f, stride 40):
//   f*40 + 0..4   : cw[k]
//   f*40 + 5..9   : iw[k]
//   f*40 + 10..14 : ch[k]
//   f*40 + 15..19 : h[k]
//   f*40 + 20..24 : dl[k]
//   f*40 + 25..29 : dr[k]
//   f*40 + 30..33 : interior boundaries b1..b4
// scalars: ws[160]=mu, ws[161]=c0, ws[162]=ivar
#define SCAL_OFF 160

__global__ void nsf_prep(const float* __restrict__ layers,
                         const float* __restrict__ ip,
                         float* __restrict__ ws) {
    const int f = threadIdx.x;
    if (f < NF) {
        const float* p = layers + f * (3 * KBINS - 1);
        float W[KBINS], H[KBINS];
        float ew[KBINS], eh[KBINS];
        float m = p[0];
        for (int i = 1; i < KBINS; ++i) m = fmaxf(m, p[i]);
        float s = 0.f;
        for (int i = 0; i < KBINS; ++i) { ew[i] = expf(p[i] - m); s += ew[i]; }
        for (int i = 0; i < KBINS; ++i) W[i] = (ew[i] / s) * (2.f * BV);
        float mh = p[KBINS];
        for (int i = 1; i < KBINS; ++i) mh = fmaxf(mh, p[KBINS + i]);
        float sh = 0.f;
        for (int i = 0; i < KBINS; ++i) { eh[i] = expf(p[KBINS + i] - mh); sh += eh[i]; }
        for (int i = 0; i < KBINS; ++i) H[i] = (eh[i] / sh) * (2.f * BV);
        float dv[KBINS + 1];
        dv[0] = 1.f;
        dv[KBINS] = 1.f;
        for (int i = 0; i < KBINS - 1; ++i)
            dv[i + 1] = 2.f / (1.f + expf(-p[2 * KBINS + i]));
        float csw = 0.f, csh = 0.f;
        float* b = ws + f * 40;
        for (int k = 0; k < KBINS; ++k) {
            b[0 + k]  = csw - BV;          // cw
            b[5 + k]  = 1.f / W[k];        // iw
            b[10 + k] = csh - BV;          // ch
            b[15 + k] = H[k];              // h
            b[20 + k] = dv[k];             // dl
            b[25 + k] = dv[k + 1];         // dr
            csw += W[k];
            csh += H[k];
            if (k < KBINS - 1) b[30 + k] = csw - BV;   // boundaries
        }
    }
    if (f == 0) {
        ws[SCAL_OFF + 0] = ip[0];
        ws[SCAL_OFF + 1] = -0.5f * logf(2.f * (float)M_PI) - 0.5f * ip[1];
        ws[SCAL_OFF + 2] = expf(-ip[1]);
    }
}

// 4-deep select tree: k>=j <=> cj  (c1>=c2>=c3>=c4 monotone)
#define SEL5(c1, c2, c3, c4, p0, p1, p2, p3, p4) \
    ((c1) ? ((c2) ? ((c3) ? ((c4) ? (p4) : (p3)) : (p2)) : (p1)) : (p0))

__global__ __launch_bounds__(256, 4) void nsf_main(
    const float* __restrict__ xin,
    const float* __restrict__ ws,
    float* __restrict__ out,
    long n) {
    const float mu = ws[SCAL_OFF + 0];
    const float c0 = ws[SCAL_OFF + 1];
    const float ivar = ws[SCAL_OFF + 2];

    const long n4 = n >> 2;
    const long q = (long)blockIdx.x * blockDim.x + threadIdx.x;

    if (q < n4) {
        const f32x4 xv = reinterpret_cast<const f32x4*>(xin)[q];
        float xc[4];
        float lda[4];
#pragma unroll
        for (int e = 0; e < 4; ++e) {
            xc[e] = fminf(fmaxf(xv[e], -BV), BV);
            lda[e] = 0.f;
        }

#pragma unroll
        for (int f = 0; f < NF; ++f) {
            const float* B = ws + f * 40;   // uniform -> s_load
            const float b1 = B[30], b2 = B[31], b3 = B[32], b4 = B[33];
#pragma unroll
            for (int e = 0; e < 4; ++e) {
                const bool c1 = (xc[e] >= b1);
                const bool c2 = (xc[e] >= b2);
                const bool c3 = (xc[e] >= b3);
                const bool c4 = (xc[e] >= b4);
                float cw = SEL5(c1, c2, c3, c4, B[0], B[1], B[2], B[3], B[4]);
                float iw = SEL5(c1, c2, c3, c4, B[5], B[6], B[7], B[8], B[9]);
                float ch = SEL5(c1, c2, c3, c4, B[10], B[11], B[12], B[13], B[14]);
                float h  = SEL5(c1, c2, c3, c4, B[15], B[16], B[17], B[18], B[19]);
                float dl = SEL5(c1, c2, c3, c4, B[20], B[21], B[22], B[23], B[24]);
                float dr = SEL5(c1, c2, c3, c4, B[25], B[26], B[27], B[28], B[29]);
                float d = h * iw;
                float s2 = fmaf(-2.f, d, dl + dr);
                float th = (xc[e] - cw) * iw;
                float omt = 1.f - th;
                float tomt = th * omt;
                float th2 = th * th;
                float den = fmaf(s2, tomt, d);
                float rden = __builtin_amdgcn_rcpf(den);
                xc[e] = fmaf(h * fmaf(d, th2, dl * tomt), rden, ch);
                float Nn = fmaf(dr, th2, fmaf(d + d, tomt, dl * (omt * omt)));
                float g = d * rden;
                lda[e] += __logf((g * g) * Nn);
            }
        }

        f32x4 v0, v1, v2;
#pragma unroll
        for (int e = 0; e < 4; ++e) {
            const bool ins = (xv[e] >= -BV) && (xv[e] <= BV);
            float xf = ins ? xc[e] : xv[e];
            float ld = ins ? lda[e] : 0.f;
            float xm = xf - mu;
            v0[e] = fmaf(-0.5f * ivar, xm * xm, c0);
            v1[e] = ld;
            v2[e] = xf;
        }
        __builtin_nontemporal_store(v0, reinterpret_cast<f32x4*>(out) + q);
        __builtin_nontemporal_store(v1, reinterpret_cast<f32x4*>(out + n) + q);
        __builtin_nontemporal_store(v2, reinterpret_cast<f32x4*>(out + 2 * n) + q);
    }

    // tail (n not divisible by 4)
    const long rem = n & 3;
    if (rem && q < rem) {
        long i = n4 * 4 + q;
        float x0 = xin[i];
        float xc = fminf(fmaxf(x0, -BV), BV);
        float lda = 0.f;
#pragma unroll
        for (int f = 0; f < NF; ++f) {
            const float* B = ws + f * 40;
            const bool c1 = (xc >= B[30]);
            const bool c2 = (xc >= B[31]);
            const bool c3 = (xc >= B[32]);
            const bool c4 = (xc >= B[33]);
            float cw = SEL5(c1, c2, c3, c4, B[0], B[1], B[2], B[3], B[4]);
            float iw = SEL5(c1, c2, c3, c4, B[5], B[6], B[7], B[8], B[9]);
            float ch = SEL5(c1, c2, c3, c4, B[10], B[11], B[12], B[13], B[14]);
            float h  = SEL5(c1, c2, c3, c4, B[15], B[16], B[17], B[18], B[19]);
            float dl = SEL5(c1, c2, c3, c4, B[20], B[21], B[22], B[23], B[24]);
            float dr = SEL5(c1, c2, c3, c4, B[25], B[26], B[27], B[28], B[29]);
            float d = h * iw;
            float s2 = fmaf(-2.f, d, dl + dr);
            float th = (xc - cw) * iw;
            float omt = 1.f - th, tomt = th * omt, th2 = th * th;
            float den = fmaf(s2, tomt, d);
            float rden = __builtin_amdgcn_rcpf(den);
            xc = fmaf(h * fmaf(d, th2, dl * tomt), rden, ch);
            float Nn = fmaf(dr, th2, fmaf(d + d, tomt, dl * (omt * omt)));
            float g = d * rden;
            lda += __logf((g * g) * Nn);
        }
        const bool ins = (x0 >= -BV) && (x0 <= BV);
        float xf = ins ? xc : x0;
        float ld = ins ? lda : 0.f;
        float xm = xf - mu;
        out[i] = fmaf(-0.5f * ivar, xm * xm, c0);
        out[n + i] = ld;
        out[2 * n + i] = xf;
    }
}

extern "C" void kernel_launch(void* const* d_in, const int* in_sizes, int n_in,
                              void* d_out, int out_size, void* d_ws, size_t ws_size,
                              hipStream_t stream) {
    const float* x = (const float*)d_in[0];
    const float* layers = (const float*)d_in[1];
    const float* ip = (const float*)d_in[2];
    float* ws = (float*)d_ws;
    float* out = (float*)d_out;
    const long n = (long)in_sizes[0];

    hipLaunchKernelGGL(nsf_prep, dim3(1), dim3(64), 0, stream, layers, ip, ws);

    const long n4 = (n + 3) >> 2;
    long blocks = (n4 + 255) / 256;
    if (blocks < 1) blocks = 1;
    hipLaunchKernelGGL(nsf_main, dim3((int)blocks), dim3(256), 0, stream, x, ws, out, n);
}

// Round 12
// 47.501 us; speedup vs baseline: 1.3468x; 1.3468x over previous
//
#include <hip/hip_runtime.h>
#include <hip/hip_bf16.h>
#include <math.h>

#define KBINS 5
#define NF 4
#define BV 3.0f

typedef float f32x4 __attribute__((ext_vector_type(4)));
typedef float f32x2 __attribute__((ext_vector_type(2)));

// LDS tbl layout (floats):
//   [0,160):   f*40 + k*8 + {cw, iw, ch, h, dl, dr, -, -}   (stride 8 for b128 align)
//   [160,176): interior boundaries: f*4 + j = cumw[j+1], j=0..3
//   [176,179): mu, c0, ivar
#define BND_OFF 160
#define SCALE32 4294967296.0f   // 2^32, exact
#define LN2F 0.693147180559945f

__global__ __launch_bounds__(256, 4) void nsf_all(
    const float* __restrict__ xin,
    const float* __restrict__ layers,
    const float* __restrict__ ip,
    float* __restrict__ out,
    unsigned int n) {
    __shared__ __align__(16) float tbl[184];
    const int t = threadIdx.x;
    // ---- in-block prep: 13 writer threads, disjoint slots ----
    if (t < 12) {
        const int f = t & 3;
        const int role = t >> 2;
        const float* p = layers + f * (3 * KBINS - 1);
        if (role == 0) {
            float e[KBINS];
            float m = p[0];
            for (int i = 1; i < KBINS; ++i) m = fmaxf(m, p[i]);
            float s = 0.f;
            for (int i = 0; i < KBINS; ++i) { e[i] = expf(p[i] - m); s += e[i]; }
            float cs = 0.f;
            for (int k = 0; k < KBINS; ++k) {
                float Wk = (e[k] / s) * (2.f * BV);
                tbl[f * 40 + k * 8 + 0] = cs - BV;
                tbl[f * 40 + k * 8 + 1] = 1.f / Wk;
                cs += Wk;
                if (k < KBINS - 1) tbl[BND_OFF + f * 4 + k] = cs - BV;
            }
        } else if (role == 1) {
            float e[KBINS];
            float m = p[KBINS];
            for (int i = 1; i < KBINS; ++i) m = fmaxf(m, p[KBINS + i]);
            float s = 0.f;
            for (int i = 0; i < KBINS; ++i) { e[i] = expf(p[KBINS + i] - m); s += e[i]; }
            float cs = 0.f;
            for (int k = 0; k < KBINS; ++k) {
                float Hk = (e[k] / s) * (2.f * BV);
                tbl[f * 40 + k * 8 + 2] = cs - BV;
                tbl[f * 40 + k * 8 + 3] = Hk;
                cs += Hk;
            }
        } else {
            float dv[KBINS + 1];
            dv[0] = 1.f;
            dv[KBINS] = 1.f;
            for (int i = 0; i < KBINS - 1; ++i)
                dv[i + 1] = 2.f / (1.f + expf(-p[2 * KBINS + i]));
            for (int k = 0; k < KBINS; ++k) {
                tbl[f * 40 + k * 8 + 4] = dv[k];
                tbl[f * 40 + k * 8 + 5] = dv[k + 1];
            }
        }
    }
    if (t == 12) {
        tbl[176] = ip[0];
        tbl[177] = -0.5f * logf(2.f * (float)M_PI) - 0.5f * ip[1];
        tbl[178] = expf(-ip[1]);
    }
    __syncthreads();

    const float mu = tbl[176];
    const float c0 = tbl[177];
    const float ivar = tbl[178];

    const unsigned int n4 = n >> 2;
    const unsigned int q = blockIdx.x * 256u + (unsigned int)threadIdx.x;

    if (q < n4) {
        const f32x4 xv = reinterpret_cast<const f32x4*>(xin)[q];
        float xc[4];
        float pa[4], pb[4];
#pragma unroll
        for (int e = 0; e < 4; ++e) {
            xc[e] = __builtin_amdgcn_fmed3f(xv[e], -BV, BV);
            pa[e] = 1.f;
            pb[e] = 1.f;
        }

#pragma unroll
        for (int f = 0; f < NF; ++f) {
            const f32x4 bb = *reinterpret_cast<const f32x4*>(&tbl[BND_OFF + f * 4]);
            f32x4 lo[4];
            f32x2 dd[4];
#pragma unroll
            for (int e = 0; e < 4; ++e) {
                int k = (xc[e] >= bb.x) + (xc[e] >= bb.y) + (xc[e] >= bb.z) + (xc[e] >= bb.w);
                const float* tt = &tbl[f * 40 + k * 8];
                lo[e] = *reinterpret_cast<const f32x4*>(tt);
                dd[e] = *reinterpret_cast<const f32x2*>(tt + 4);
            }
#pragma unroll
            for (int e = 0; e < 4; ++e) {
                float cw = lo[e].x, iw = lo[e].y, ch = lo[e].z, h = lo[e].w;
                float dl = dd[e].x, dr = dd[e].y;
                float d = h * iw;
                float s2 = fmaf(-2.f, d, dl + dr);
                float th = (xc[e] - cw) * iw;
                float omt = 1.f - th;
                float tomt = th * omt;
                float th2 = th * th;
                float den = fmaf(s2, tomt, d);
                float rden = __builtin_amdgcn_rcpf(den);
                xc[e] = fmaf(h * fmaf(d, th2, dl * tomt), rden, ch);
                float Nn = fmaf(dr, th2, fmaf(d + d, tomt, dl * (omt * omt)));
                float g = d * rden;
                float r = (g * g) * Nn;
                if (f == 0) pa[e] *= r;
                else if (f == 1) pa[e] *= r * SCALE32;
                else if (f == 2) pb[e] *= r;
                else pb[e] *= r * SCALE32;
            }
        }

        f32x4 v0, v1, v2;
#pragma unroll
        for (int e = 0; e < 4; ++e) {
            const bool ins = (fabsf(xv[e]) <= BV);
            float xf = ins ? xc[e] : xv[e];
            // log2 accumulate: v_log_f32 native; SCALE32 correction exactly 64
            float l2 = __log2f(pa[e]) + (__log2f(pb[e]) - 64.f);
            float ld = ins ? l2 * LN2F : 0.f;
            float xm = xf - mu;
            v0[e] = fmaf(-0.5f * ivar, xm * xm, c0);
            v1[e] = ld;
            v2[e] = xf;
        }
        __builtin_nontemporal_store(v0, reinterpret_cast<f32x4*>(out) + q);
        __builtin_nontemporal_store(v1, reinterpret_cast<f32x4*>(out + n) + q);
        __builtin_nontemporal_store(v2, reinterpret_cast<f32x4*>(out + 2 * n) + q);
    }

    // tail (n not divisible by 4; n = 2^23 here so normally empty)
    const unsigned int rem = n & 3u;
    if (rem && q < rem) {
        unsigned int i = n4 * 4 + q;
        float x0 = xin[i];
        float xc = __builtin_amdgcn_fmed3f(x0, -BV, BV);
        float pa = 1.f, pb = 1.f;
#pragma unroll
        for (int f = 0; f < NF; ++f) {
            const float* bbp = &tbl[BND_OFF + f * 4];
            int k = (xc >= bbp[0]) + (xc >= bbp[1]) + (xc >= bbp[2]) + (xc >= bbp[3]);
            const float* tt = &tbl[f * 40 + k * 8];
            float cw = tt[0], iw = tt[1], ch = tt[2], h = tt[3];
            float dl = tt[4], dr = tt[5];
            float d = h * iw;
            float s2 = fmaf(-2.f, d, dl + dr);
            float th = (xc - cw) * iw;
            float omt = 1.f - th, tomt = th * omt, th2 = th * th;
            float den = fmaf(s2, tomt, d);
            float rden = __builtin_amdgcn_rcpf(den);
            xc = fmaf(h * fmaf(d, th2, dl * tomt), rden, ch);
            float Nn = fmaf(dr, th2, fmaf(d + d, tomt, dl * (omt * omt)));
            float g = d * rden;
            float r = (g * g) * Nn;
            if (f == 0) pa *= r;
            else if (f == 1) pa *= r * SCALE32;
            else if (f == 2) pb *= r;
            else pb *= r * SCALE32;
        }
        const bool ins = (fabsf(x0) <= BV);
        float xf = ins ? xc : x0;
        float l2 = __log2f(pa) + (__log2f(pb) - 64.f);
        float ld = ins ? l2 * LN2F : 0.f;
        float xm = xf - mu;
        out[i] = fmaf(-0.5f * ivar, xm * xm, c0);
        out[n + i] = ld;
        out[2 * n + i] = xf;
    }
}

extern "C" void kernel_launch(void* const* d_in, const int* in_sizes, int n_in,
                              void* d_out, int out_size, void* d_ws, size_t ws_size,
                              hipStream_t stream) {
    const float* x = (const float*)d_in[0];
    const float* layers = (const float*)d_in[1];
    const float* ip = (const float*)d_in[2];
    float* out = (float*)d_out;
    const unsigned int n = (unsigned int)in_sizes[0];

    const unsigned int n4 = (n + 3u) >> 2;
    unsigned int blocks = (n4 + 255u) / 256u;
    if (blocks < 1u) blocks = 1u;
    hipLaunchKernelGGL(nsf_all, dim3(blocks), dim3(256), 0, stream, x, layers, ip, out, n);
}

// Round 13
// 46.381 us; speedup vs baseline: 1.3793x; 1.0241x over previous
//
#include <hip/hip_runtime.h>
#include <hip/hip_bf16.h>
#include <math.h>

#define KBINS 5
#define NF 4
#define BV 3.0f

typedef float f32x4 __attribute__((ext_vector_type(4)));

// LDS tbl layout (floats):
//   [0,160):   f*40 + k*8 + {cw, iw, ch, h, dl, dr, d, s2}
//   [160,176): interior boundaries: f*4 + j = cumw[j+1], j=0..3
//   [176,179): mu, c0, ivar
#define BND_OFF 160
#define SCALE32 4294967296.0f    // 2^32, exact
#define LN2F 0.693147180559945f
#define NEG64LN2F -44.3614195558364798f  // -64*ln2

__global__ __launch_bounds__(256, 4) void nsf_all(
    const float* __restrict__ xin,
    const float* __restrict__ layers,
    const float* __restrict__ ip,
    float* __restrict__ out,
    unsigned int n) {
    __shared__ __align__(16) float tbl[184];
    const int t = threadIdx.x;
    // ---- prep phase 1: 13 writer threads, disjoint slots ----
    if (t < 12) {
        const int f = t & 3;
        const int role = t >> 2;
        const float* p = layers + f * (3 * KBINS - 1);
        if (role == 0) {
            float e[KBINS];
            float m = p[0];
            for (int i = 1; i < KBINS; ++i) m = fmaxf(m, p[i]);
            float s = 0.f;
            for (int i = 0; i < KBINS; ++i) { e[i] = expf(p[i] - m); s += e[i]; }
            float cs = 0.f;
            for (int k = 0; k < KBINS; ++k) {
                float Wk = (e[k] / s) * (2.f * BV);
                tbl[f * 40 + k * 8 + 0] = cs - BV;
                tbl[f * 40 + k * 8 + 1] = 1.f / Wk;
                cs += Wk;
                if (k < KBINS - 1) tbl[BND_OFF + f * 4 + k] = cs - BV;
            }
        } else if (role == 1) {
            float e[KBINS];
            float m = p[KBINS];
            for (int i = 1; i < KBINS; ++i) m = fmaxf(m, p[KBINS + i]);
            float s = 0.f;
            for (int i = 0; i < KBINS; ++i) { e[i] = expf(p[KBINS + i] - m); s += e[i]; }
            float cs = 0.f;
            for (int k = 0; k < KBINS; ++k) {
                float Hk = (e[k] / s) * (2.f * BV);
                tbl[f * 40 + k * 8 + 2] = cs - BV;
                tbl[f * 40 + k * 8 + 3] = Hk;
                cs += Hk;
            }
        } else {
            float dv[KBINS + 1];
            dv[0] = 1.f;
            dv[KBINS] = 1.f;
            for (int i = 0; i < KBINS - 1; ++i)
                dv[i + 1] = 2.f / (1.f + expf(-p[2 * KBINS + i]));
            for (int k = 0; k < KBINS; ++k) {
                tbl[f * 40 + k * 8 + 4] = dv[k];
                tbl[f * 40 + k * 8 + 5] = dv[k + 1];
            }
        }
    }
    if (t == 12) {
        tbl[176] = ip[0];
        tbl[177] = -0.5f * logf(2.f * (float)M_PI) - 0.5f * ip[1];
        tbl[178] = expf(-ip[1]);
    }
    __syncthreads();
    // ---- prep phase 2: derived per-bin d, s2 ----
    if (t < 32) {
        const int f = t >> 3, k = t & 7;
        if (k < KBINS) {
            float* b = &tbl[f * 40 + k * 8];
            float d = b[3] * b[1];               // h * iw
            b[6] = d;
            b[7] = fmaf(-2.f, d, b[4] + b[5]);   // dl+dr-2d
        }
    }
    __syncthreads();

    const float mu = tbl[176];
    const float c0 = tbl[177];
    const float ivar = tbl[178];

    const unsigned int n4 = n >> 2;
    const unsigned int q = blockIdx.x * 256u + (unsigned int)threadIdx.x;

    if (q < n4) {
        const f32x4 xv = reinterpret_cast<const f32x4*>(xin)[q];
        float xc[4];
        float pa[4], pb[4];
#pragma unroll
        for (int e = 0; e < 4; ++e) {
            xc[e] = __builtin_amdgcn_fmed3f(xv[e], -BV, BV);
            pa[e] = 1.f;
            pb[e] = 1.f;
        }

#pragma unroll
        for (int f = 0; f < NF; ++f) {
            const f32x4 bb = *reinterpret_cast<const f32x4*>(&tbl[BND_OFF + f * 4]);
            f32x4 lo[4];
            const float* tp[4];
#pragma unroll
            for (int e = 0; e < 4; ++e) {
                int k = (xc[e] >= bb.x) + (xc[e] >= bb.y) + (xc[e] >= bb.z) + (xc[e] >= bb.w);
                tp[e] = &tbl[f * 40 + k * 8];
                lo[e] = *reinterpret_cast<const f32x4*>(tp[e]);
            }
#pragma unroll
            for (int e = 0; e < 4; ++e) {
                const f32x4 hi = *reinterpret_cast<const f32x4*>(tp[e] + 4);
                float cw = lo[e].x, iw = lo[e].y, ch = lo[e].z, h = lo[e].w;
                float dl = hi.x, dr = hi.y, d = hi.z, s2 = hi.w;
                float th = (xc[e] - cw) * iw;
                float omt = 1.f - th;
                float tomt = th * omt;
                float th2 = th * th;
                float den = fmaf(s2, tomt, d);
                float rden = __builtin_amdgcn_rcpf(den);
                xc[e] = fmaf(h * fmaf(d, th2, dl * tomt), rden, ch);
                float Nn = fmaf(dr, th2, fmaf(d + d, tomt, dl * (omt * omt)));
                float g = d * rden;
                float r = (g * g) * Nn;
                if (f == 0) pa[e] *= r;
                else if (f == 1) pa[e] *= r * SCALE32;
                else if (f == 2) pb[e] *= r;
                else pb[e] *= r * SCALE32;
            }
        }

        f32x4 v0, v1, v2;
#pragma unroll
        for (int e = 0; e < 4; ++e) {
            const bool ins = (fabsf(xv[e]) <= BV);
            float xf = ins ? xc[e] : xv[e];
            float l2 = __log2f(pa[e]) + __log2f(pb[e]);
            float ld = ins ? fmaf(l2, LN2F, NEG64LN2F) : 0.f;
            float xm = xf - mu;
            v0[e] = fmaf(-0.5f * ivar, xm * xm, c0);
            v1[e] = ld;
            v2[e] = xf;
        }
        __builtin_nontemporal_store(v0, reinterpret_cast<f32x4*>(out) + q);
        __builtin_nontemporal_store(v1, reinterpret_cast<f32x4*>(out + n) + q);
        __builtin_nontemporal_store(v2, reinterpret_cast<f32x4*>(out + 2 * n) + q);
    }

    // tail (n not divisible by 4; n = 2^23 here so normally empty)
    const unsigned int rem = n & 3u;
    if (rem && q < rem) {
        unsigned int i = n4 * 4 + q;
        float x0 = xin[i];
        float xc = __builtin_amdgcn_fmed3f(x0, -BV, BV);
        float pa = 1.f, pb = 1.f;
#pragma unroll
        for (int f = 0; f < NF; ++f) {
            const float* bbp = &tbl[BND_OFF + f * 4];
            int k = (xc >= bbp[0]) + (xc >= bbp[1]) + (xc >= bbp[2]) + (xc >= bbp[3]);
            const float* tt = &tbl[f * 40 + k * 8];
            float cw = tt[0], iw = tt[1], ch = tt[2], h = tt[3];
            float dl = tt[4], dr = tt[5], d = tt[6], s2 = tt[7];
            float th = (xc - cw) * iw;
            float omt = 1.f - th, tomt = th * omt, th2 = th * th;
            float den = fmaf(s2, tomt, d);
            float rden = __builtin_amdgcn_rcpf(den);
            xc = fmaf(h * fmaf(d, th2, dl * tomt), rden, ch);
            float Nn = fmaf(dr, th2, fmaf(d + d, tomt, dl * (omt * omt)));
            float g = d * rden;
            float r = (g * g) * Nn;
            if (f == 0) pa *= r;
            else if (f == 1) pa *= r * SCALE32;
            else if (f == 2) pb *= r;
            else pb *= r * SCALE32;
        }
        const bool ins = (fabsf(x0) <= BV);
        float xf = ins ? xc : x0;
        float l2 = __log2f(pa) + __log2f(pb);
        float ld = ins ? fmaf(l2, LN2F, NEG64LN2F) : 0.f;
        float xm = xf - mu;
        out[i] = fmaf(-0.5f * ivar, xm * xm, c0);
        out[n + i] = ld;
        out[2 * n + i] = xf;
    }
}

extern "C" void kernel_launch(void* const* d_in, const int* in_sizes, int n_in,
                              void* d_out, int out_size, void* d_ws, size_t ws_size,
                              hipStream_t stream) {
    const float* x = (const float*)d_in[0];
    const float* layers = (const float*)d_in[1];
    const float* ip = (const float*)d_in[2];
    float* out = (float*)d_out;
    const unsigned int n = (unsigned int)in_sizes[0];

    const unsigned int n4 = (n + 3u) >> 2;
    unsigned int blocks = (n4 + 255u) / 256u;
    if (blocks < 1u) blocks = 1u;
    hipLaunchKernelGGL(nsf_all, dim3(blocks), dim3(256), 0, stream, x, layers, ip, out, n);
}

// Round 14
// 43.079 us; speedup vs baseline: 1.4851x; 1.0767x over previous
//
#include <hip/hip_runtime.h>
#include <hip/hip_bf16.h>
#include <math.h>

#define KBINS 5
#define NF 4
#define BV 3.0f

typedef float f32x4 __attribute__((ext_vector_type(4)));
typedef float f32x2 __attribute__((ext_vector_type(2)));
#define FMA2(a, b, c) __builtin_elementwise_fma((f32x2)(a), (f32x2)(b), (f32x2)(c))

// LDS tbl layout (floats):
//   [0,160):   f*40 + k*8 + {cw, iw, ch, h, dl, dr, d, s2}
//   [160,176): interior boundaries: f*4 + j = cumw[j+1], j=0..3
//   [176,179): mu, c0, ivar
#define BND_OFF 160
#define SCALE32 4294967296.0f    // 2^32, exact
#define LN2F 0.693147180559945f
#define NEG64LN2F -44.3614195558364798f  // -64*ln2

__global__ __launch_bounds__(256, 4) void nsf_all(
    const float* __restrict__ xin,
    const float* __restrict__ layers,
    const float* __restrict__ ip,
    float* __restrict__ out,
    unsigned int n) {
    __shared__ __align__(16) float tbl[184];
    const int t = threadIdx.x;
    // ---- prep phase 1: 13 writer threads, disjoint slots ----
    if (t < 12) {
        const int f = t & 3;
        const int role = t >> 2;
        const float* p = layers + f * (3 * KBINS - 1);
        if (role == 0) {
            float e[KBINS];
            float m = p[0];
            for (int i = 1; i < KBINS; ++i) m = fmaxf(m, p[i]);
            float s = 0.f;
            for (int i = 0; i < KBINS; ++i) { e[i] = expf(p[i] - m); s += e[i]; }
            float cs = 0.f;
            for (int k = 0; k < KBINS; ++k) {
                float Wk = (e[k] / s) * (2.f * BV);
                tbl[f * 40 + k * 8 + 0] = cs - BV;
                tbl[f * 40 + k * 8 + 1] = 1.f / Wk;
                cs += Wk;
                if (k < KBINS - 1) tbl[BND_OFF + f * 4 + k] = cs - BV;
            }
        } else if (role == 1) {
            float e[KBINS];
            float m = p[KBINS];
            for (int i = 1; i < KBINS; ++i) m = fmaxf(m, p[KBINS + i]);
            float s = 0.f;
            for (int i = 0; i < KBINS; ++i) { e[i] = expf(p[KBINS + i] - m); s += e[i]; }
            float cs = 0.f;
            for (int k = 0; k < KBINS; ++k) {
                float Hk = (e[k] / s) * (2.f * BV);
                tbl[f * 40 + k * 8 + 2] = cs - BV;
                tbl[f * 40 + k * 8 + 3] = Hk;
                cs += Hk;
            }
        } else {
            float dv[KBINS + 1];
            dv[0] = 1.f;
            dv[KBINS] = 1.f;
            for (int i = 0; i < KBINS - 1; ++i)
                dv[i + 1] = 2.f / (1.f + expf(-p[2 * KBINS + i]));
            for (int k = 0; k < KBINS; ++k) {
                tbl[f * 40 + k * 8 + 4] = dv[k];
                tbl[f * 40 + k * 8 + 5] = dv[k + 1];
            }
        }
    }
    if (t == 12) {
        tbl[176] = ip[0];
        tbl[177] = -0.5f * logf(2.f * (float)M_PI) - 0.5f * ip[1];
        tbl[178] = expf(-ip[1]);
    }
    __syncthreads();
    // ---- prep phase 2: derived per-bin d, s2 ----
    if (t < 32) {
        const int f = t >> 3, k = t & 7;
        if (k < KBINS) {
            float* b = &tbl[f * 40 + k * 8];
            float d = b[3] * b[1];               // h * iw
            b[6] = d;
            b[7] = fmaf(-2.f, d, b[4] + b[5]);   // dl+dr-2d
        }
    }
    __syncthreads();

    const float mu = tbl[176];
    const float c0 = tbl[177];
    const float ivar = tbl[178];

    const unsigned int n4 = n >> 2;
    const unsigned int q = blockIdx.x * 256u + (unsigned int)threadIdx.x;

    if (q < n4) {
        const f32x4 xv = reinterpret_cast<const f32x4*>(xin)[q];
        f32x2 xc2[2];
        f32x2 pa2[2], pb2[2];
        xc2[0] = (f32x2){__builtin_amdgcn_fmed3f(xv.x, -BV, BV),
                         __builtin_amdgcn_fmed3f(xv.y, -BV, BV)};
        xc2[1] = (f32x2){__builtin_amdgcn_fmed3f(xv.z, -BV, BV),
                         __builtin_amdgcn_fmed3f(xv.w, -BV, BV)};
        pa2[0] = (f32x2){1.f, 1.f};
        pa2[1] = (f32x2){1.f, 1.f};
        pb2[0] = (f32x2){1.f, 1.f};
        pb2[1] = (f32x2){1.f, 1.f};

#pragma unroll
        for (int f = 0; f < NF; ++f) {
            const f32x4 bb = *reinterpret_cast<const f32x4*>(&tbl[BND_OFF + f * 4]);
            f32x4 lo[4], hi[4];
#pragma unroll
            for (int e = 0; e < 4; ++e) {
                const float xs = (e & 1) ? xc2[e >> 1].y : xc2[e >> 1].x;
                int k = (xs >= bb.x) + (xs >= bb.y) + (xs >= bb.z) + (xs >= bb.w);
                const float* tt = &tbl[f * 40 + k * 8];
                lo[e] = *reinterpret_cast<const f32x4*>(tt);
                hi[e] = *reinterpret_cast<const f32x4*>(tt + 4);
            }
#pragma unroll
            for (int pr = 0; pr < 2; ++pr) {
                const int e0 = pr * 2, e1 = e0 + 1;
                f32x2 cw = {lo[e0].x, lo[e1].x};
                f32x2 iw = {lo[e0].y, lo[e1].y};
                f32x2 ch = {lo[e0].z, lo[e1].z};
                f32x2 h  = {lo[e0].w, lo[e1].w};
                f32x2 dl = {hi[e0].x, hi[e1].x};
                f32x2 dr = {hi[e0].y, hi[e1].y};
                f32x2 d  = {hi[e0].z, hi[e1].z};
                f32x2 s2 = {hi[e0].w, hi[e1].w};
                f32x2 th = (xc2[pr] - cw) * iw;
                f32x2 omt = 1.f - th;
                f32x2 tomt = th * omt;
                f32x2 th2 = th * th;
                f32x2 den = FMA2(s2, tomt, d);
                f32x2 rden = {__builtin_amdgcn_rcpf(den.x),
                              __builtin_amdgcn_rcpf(den.y)};
                xc2[pr] = FMA2(h * FMA2(d, th2, dl * tomt), rden, ch);
                f32x2 Nn = FMA2(dr, th2, FMA2(d + d, tomt, dl * (omt * omt)));
                f32x2 g = d * rden;
                f32x2 r = (g * g) * Nn;
                if (f == 0) pa2[pr] *= r;
                else if (f == 1) pa2[pr] *= r * SCALE32;
                else if (f == 2) pb2[pr] *= r;
                else pb2[pr] *= r * SCALE32;
            }
        }

        f32x4 v0, v1, v2;
        const float xva[4] = {xv.x, xv.y, xv.z, xv.w};
#pragma unroll
        for (int e = 0; e < 4; ++e) {
            const float xce = (e & 1) ? xc2[e >> 1].y : xc2[e >> 1].x;
            const float pae = (e & 1) ? pa2[e >> 1].y : pa2[e >> 1].x;
            const float pbe = (e & 1) ? pb2[e >> 1].y : pb2[e >> 1].x;
            const bool ins = (fabsf(xva[e]) <= BV);
            float xf = ins ? xce : xva[e];
            float l2 = __log2f(pae) + __log2f(pbe);
            float ld = ins ? fmaf(l2, LN2F, NEG64LN2F) : 0.f;
            float xm = xf - mu;
            v0[e] = fmaf(-0.5f * ivar, xm * xm, c0);
            v1[e] = ld;
            v2[e] = xf;
        }
        __builtin_nontemporal_store(v0, reinterpret_cast<f32x4*>(out) + q);
        __builtin_nontemporal_store(v1, reinterpret_cast<f32x4*>(out + n) + q);
        __builtin_nontemporal_store(v2, reinterpret_cast<f32x4*>(out + 2 * n) + q);
    }

    // tail (n not divisible by 4; n = 2^23 here so normally empty)
    const unsigned int rem = n & 3u;
    if (rem && q < rem) {
        unsigned int i = n4 * 4 + q;
        float x0 = xin[i];
        float xc = __builtin_amdgcn_fmed3f(x0, -BV, BV);
        float pa = 1.f, pb = 1.f;
#pragma unroll
        for (int f = 0; f < NF; ++f) {
            const float* bbp = &tbl[BND_OFF + f * 4];
            int k = (xc >= bbp[0]) + (xc >= bbp[1]) + (xc >= bbp[2]) + (xc >= bbp[3]);
            const float* tt = &tbl[f * 40 + k * 8];
            float cw = tt[0], iw = tt[1], ch = tt[2], h = tt[3];
            float dl = tt[4], dr = tt[5], d = tt[6], s2 = tt[7];
            float th = (xc - cw) * iw;
            float omt = 1.f - th, tomt = th * omt, th2 = th * th;
            float den = fmaf(s2, tomt, d);
            float rden = __builtin_amdgcn_rcpf(den);
            xc = fmaf(h * fmaf(d, th2, dl * tomt), rden, ch);
            float Nn = fmaf(dr, th2, fmaf(d + d, tomt, dl * (omt * omt)));
            float g = d * rden;
            float r = (g * g) * Nn;
            if (f == 0) pa *= r;
            else if (f == 1) pa *= r * SCALE32;
            else if (f == 2) pb *= r;
            else pb *= r * SCALE32;
        }
        const bool ins = (fabsf(x0) <= BV);
        float xf = ins ? xc : x0;
        float l2 = __log2f(pa) + __log2f(pb);
        float ld = ins ? fmaf(l2, LN2F, NEG64LN2F) : 0.f;
        float xm = xf - mu;
        out[i] = fmaf(-0.5f * ivar, xm * xm, c0);
        out[n + i] = ld;
        out[2 * n + i] = xf;
    }
}

extern "C" void kernel_launch(void* const* d_in, const int* in_sizes, int n_in,
                              void* d_out, int out_size, void* d_ws, size_t ws_size,
                              hipStream_t stream) {
    const float* x = (const float*)d_in[0];
    const float* layers = (const float*)d_in[1];
    const float* ip = (const float*)d_in[2];
    float* out = (float*)d_out;
    const unsigned int n = (unsigned int)in_sizes[0];

    const unsigned int n4 = (n + 3u) >> 2;
    unsigned int blocks = (n4 + 255u) / 256u;
    if (blocks < 1u) blocks = 1u;
    hipLaunchKernelGGL(nsf_all, dim3(blocks), dim3(256), 0, stream, x, layers, ip, out, n);
}

// Round 16
// 40.441 us; speedup vs baseline: 1.5820x; 1.0652x over previous
//
#include <hip/hip_runtime.h>
#include <hip/hip_bf16.h>
#include <math.h>

#define KBINS 5
#define NF 4
#define BV 3.0f

typedef float f32x4 __attribute__((ext_vector_type(4)));
typedef float f32x2 __attribute__((ext_vector_type(2)));
#define FMA2(a, b, c) __builtin_elementwise_fma((f32x2)(a), (f32x2)(b), (f32x2)(c))

// ws/tbl layout (floats):
//   [0,160):   f*40 + k*8 + {cw, iw, ch, h, dl, dr, d, s2}
//   [160,176): interior boundaries: f*4 + j = cumw[j+1], j=0..3
//   [176,179): mu, c0, ivar   (179..183 pad)
#define BND_OFF 160
#define SCALE32 4294967296.0f    // 2^32, exact
#define LN2F 0.693147180559945f
#define NEG64LN2F -44.3614195558364798f  // -64*ln2

__global__ void nsf_prep(const float* __restrict__ layers,
                         const float* __restrict__ ip,
                         float* __restrict__ ws) {
    const int f = threadIdx.x;
    if (f < NF) {
        const float* p = layers + f * (3 * KBINS - 1);
        float W[KBINS], H[KBINS], e[KBINS];
        float m = p[0];
        for (int i = 1; i < KBINS; ++i) m = fmaxf(m, p[i]);
        float s = 0.f;
        for (int i = 0; i < KBINS; ++i) { e[i] = expf(p[i] - m); s += e[i]; }
        for (int i = 0; i < KBINS; ++i) W[i] = (e[i] / s) * (2.f * BV);
        float mh = p[KBINS];
        for (int i = 1; i < KBINS; ++i) mh = fmaxf(mh, p[KBINS + i]);
        float sh = 0.f;
        for (int i = 0; i < KBINS; ++i) { e[i] = expf(p[KBINS + i] - mh); sh += e[i]; }
        for (int i = 0; i < KBINS; ++i) H[i] = (e[i] / sh) * (2.f * BV);
        float dv[KBINS + 1];
        dv[0] = 1.f;
        dv[KBINS] = 1.f;
        for (int i = 0; i < KBINS - 1; ++i)
            dv[i + 1] = 2.f / (1.f + expf(-p[2 * KBINS + i]));
        float csw = 0.f, csh = 0.f;
        for (int k = 0; k < KBINS; ++k) {
            float* b = ws + f * 40 + k * 8;
            float iwv = 1.f / W[k];
            float d = H[k] * iwv;
            b[0] = csw - BV;
            b[1] = iwv;
            b[2] = csh - BV;
            b[3] = H[k];
            b[4] = dv[k];
            b[5] = dv[k + 1];
            b[6] = d;
            b[7] = fmaf(-2.f, d, dv[k] + dv[k + 1]);
            csw += W[k];
            csh += H[k];
            if (k < KBINS - 1) ws[BND_OFF + f * 4 + k] = csw - BV;
        }
    }
    if (f == 0) {
        ws[176] = ip[0];
        ws[177] = -0.5f * logf(2.f * (float)M_PI) - 0.5f * ip[1];
        ws[178] = expf(-ip[1]);
        ws[179] = 0.f; ws[180] = 0.f; ws[181] = 0.f; ws[182] = 0.f; ws[183] = 0.f;
    }
}

__global__ __launch_bounds__(256, 4) void nsf_main(
    const float* __restrict__ xin,
    const float* __restrict__ ws,
    float* __restrict__ out,
    unsigned int n) {
    __shared__ __align__(16) float tbl[184];
    const int t = threadIdx.x;
    if (t < 46)
        reinterpret_cast<f32x4*>(tbl)[t] = reinterpret_cast<const f32x4*>(ws)[t];
    __syncthreads();

    const float mu = tbl[176];
    const float c0 = tbl[177];
    const float ivar = tbl[178];

    const unsigned int n4 = n >> 2;
    const unsigned int q = blockIdx.x * 256u + (unsigned int)threadIdx.x;

    if (q < n4) {
        const f32x4 xv = reinterpret_cast<const f32x4*>(xin)[q];
        f32x2 xc2[2];
        f32x2 pa2[2], pb2[2];
        xc2[0] = (f32x2){__builtin_amdgcn_fmed3f(xv.x, -BV, BV),
                         __builtin_amdgcn_fmed3f(xv.y, -BV, BV)};
        xc2[1] = (f32x2){__builtin_amdgcn_fmed3f(xv.z, -BV, BV),
                         __builtin_amdgcn_fmed3f(xv.w, -BV, BV)};
        pa2[0] = (f32x2){1.f, 1.f};
        pa2[1] = (f32x2){1.f, 1.f};
        pb2[0] = (f32x2){1.f, 1.f};
        pb2[1] = (f32x2){1.f, 1.f};

#pragma unroll
        for (int f = 0; f < NF; ++f) {
            const f32x4 bb = *reinterpret_cast<const f32x4*>(&tbl[BND_OFF + f * 4]);
            f32x4 lo[4], hi[4];
#pragma unroll
            for (int e = 0; e < 4; ++e) {
                const float xs = (e & 1) ? xc2[e >> 1].y : xc2[e >> 1].x;
                int k = (xs >= bb.x) + (xs >= bb.y) + (xs >= bb.z) + (xs >= bb.w);
                const float* tt = &tbl[f * 40 + k * 8];
                lo[e] = *reinterpret_cast<const f32x4*>(tt);
                hi[e] = *reinterpret_cast<const f32x4*>(tt + 4);
            }
#pragma unroll
            for (int pr = 0; pr < 2; ++pr) {
                const int e0 = pr * 2, e1 = e0 + 1;
                f32x2 cw = {lo[e0].x, lo[e1].x};
                f32x2 iw = {lo[e0].y, lo[e1].y};
                f32x2 ch = {lo[e0].z, lo[e1].z};
                f32x2 h  = {lo[e0].w, lo[e1].w};
                f32x2 dl = {hi[e0].x, hi[e1].x};
                f32x2 dr = {hi[e0].y, hi[e1].y};
                f32x2 d  = {hi[e0].z, hi[e1].z};
                f32x2 s2 = {hi[e0].w, hi[e1].w};
                f32x2 th = (xc2[pr] - cw) * iw;
                f32x2 omt = 1.f - th;
                f32x2 tomt = th * omt;
                f32x2 th2 = th * th;
                f32x2 den = FMA2(s2, tomt, d);
                f32x2 rden = {__builtin_amdgcn_rcpf(den.x),
                              __builtin_amdgcn_rcpf(den.y)};
                xc2[pr] = FMA2(h * FMA2(d, th2, dl * tomt), rden, ch);
                f32x2 Nn = FMA2(dr, th2, FMA2(d + d, tomt, dl * (omt * omt)));
                f32x2 g = d * rden;
                f32x2 r = (g * g) * Nn;
                if (f == 0) pa2[pr] *= r;
                else if (f == 1) pa2[pr] *= r * SCALE32;
                else if (f == 2) pb2[pr] *= r;
                else pb2[pr] *= r * SCALE32;
            }
        }

        f32x4 v0, v1, v2;
        const f32x2 xv2[2] = {{xv.x, xv.y}, {xv.z, xv.w}};
        const f32x2 ln2v = {LN2F, LN2F};
        const f32x2 n64v = {NEG64LN2F, NEG64LN2F};
        const f32x2 nhiv = {-0.5f * ivar, -0.5f * ivar};
        const f32x2 c0v = {c0, c0};
#pragma unroll
        for (int pr = 0; pr < 2; ++pr) {
            const bool ins0 = (fabsf(xv2[pr].x) <= BV);
            const bool ins1 = (fabsf(xv2[pr].y) <= BV);
            f32x2 l2 = {__log2f(pa2[pr].x) + __log2f(pb2[pr].x),
                        __log2f(pa2[pr].y) + __log2f(pb2[pr].y)};
            f32x2 ldv = FMA2(l2, ln2v, n64v);
            f32x2 xf = {ins0 ? xc2[pr].x : xv2[pr].x,
                        ins1 ? xc2[pr].y : xv2[pr].y};
            f32x2 xm = xf - mu;
            f32x2 xm2 = xm * xm;
            f32x2 lp = FMA2(nhiv, xm2, c0v);
            v0[pr * 2]     = lp.x;
            v0[pr * 2 + 1] = lp.y;
            v1[pr * 2]     = ins0 ? ldv.x : 0.f;
            v1[pr * 2 + 1] = ins1 ? ldv.y : 0.f;
            v2[pr * 2]     = xf.x;
            v2[pr * 2 + 1] = xf.y;
        }
        __builtin_nontemporal_store(v0, reinterpret_cast<f32x4*>(out) + q);
        __builtin_nontemporal_store(v1, reinterpret_cast<f32x4*>(out + n) + q);
        __builtin_nontemporal_store(v2, reinterpret_cast<f32x4*>(out + 2 * n) + q);
    }

    // tail (n not divisible by 4; n = 2^23 here so normally empty)
    const unsigned int rem = n & 3u;
    if (rem && q < rem) {
        unsigned int i = n4 * 4 + q;
        float x0 = xin[i];
        float xc = __builtin_amdgcn_fmed3f(x0, -BV, BV);
        float pa = 1.f, pb = 1.f;
#pragma unroll
        for (int f = 0; f < NF; ++f) {
            const float* bbp = &tbl[BND_OFF + f * 4];
            int k = (xc >= bbp[0]) + (xc >= bbp[1]) + (xc >= bbp[2]) + (xc >= bbp[3]);
            const float* tt = &tbl[f * 40 + k * 8];
            float cw = tt[0], iw = tt[1], ch = tt[2], h = tt[3];
            float dl = tt[4], dr = tt[5], d = tt[6], s2 = tt[7];
            float th = (xc - cw) * iw;
            float omt = 1.f - th, tomt = th * omt, th2 = th * th;
            float den = fmaf(s2, tomt, d);
            float rden = __builtin_amdgcn_rcpf(den);
            xc = fmaf(h * fmaf(d, th2, dl * tomt), rden, ch);
            float Nn = fmaf(dr, th2, fmaf(d + d, tomt, dl * (omt * omt)));
            float g = d * rden;
            float r = (g * g) * Nn;
            if (f == 0) pa *= r;
            else if (f == 1) pa *= r * SCALE32;
            else if (f == 2) pb *= r;
            else pb *= r * SCALE32;
        }
        const bool ins = (fabsf(x0) <= BV);
        float xf = ins ? xc : x0;
        float l2 = __log2f(pa) + __log2f(pb);
        float ld = ins ? fmaf(l2, LN2F, NEG64LN2F) : 0.f;
        float xm = xf - mu;
        out[i] = fmaf(-0.5f * ivar, xm * xm, c0);
        out[n + i] = ld;
        out[2 * n + i] = xf;
    }
}

extern "C" void kernel_launch(void* const* d_in, const int* in_sizes, int n_in,
                              void* d_out, int out_size, void* d_ws, size_t ws_size,
                              hipStream_t stream) {
    const float* x = (const float*)d_in[0];
    const float* layers = (const float*)d_in[1];
    const float* ip = (const float*)d_in[2];
    float* ws = (float*)d_ws;
    float* out = (float*)d_out;
    const unsigned int n = (unsigned int)in_sizes[0];

    hipLaunchKernelGGL(nsf_prep, dim3(1), dim3(64), 0, stream, layers, ip, ws);

    const unsigned int n4 = (n + 3u) >> 2;
    unsigned int blocks = (n4 + 255u) / 256u;
    if (blocks < 1u) blocks = 1u;
    hipLaunchKernelGGL(nsf_main, dim3(blocks), dim3(256), 0, stream, x, ws, out, n);
}

// Round 17
// 36.116 us; speedup vs baseline: 1.7714x; 1.1197x over previous
//
#include <hip/hip_runtime.h>
#include <hip/hip_bf16.h>
#include <math.h>

#define KBINS 5
#define NF 4
#define BV 3.0f

typedef float f32x4 __attribute__((ext_vector_type(4)));
typedef float f32x2 __attribute__((ext_vector_type(2)));
#define FMA2(a, b, c) __builtin_elementwise_fma((f32x2)(a), (f32x2)(b), (f32x2)(c))

// ws/tbl layout (floats):
//   [0,2000):    combo tables: f*500 + (k0*5+k1)*20 +
//                {cw0,cw1, iw0,iw1, ch0,ch1, h0,h1, dl0,dl1, dr0,dr1, d0,d1, s20,s21, pad*4}
//   [2000,2016): interior boundaries: f*4 + j
//   [2016,2019): mu, c0, ivar  (2019 pad)
#define BND_OFF 2000
#define SCAL_OFF 2016
#define CT_V4 505            // 2020 floats / 4
#define SCALE32 4294967296.0f
#define LN2F 0.693147180559945f
#define NEG64LN2F -44.3614195558364798f

__global__ void nsf_prep(const float* __restrict__ layers,
                         const float* __restrict__ ip,
                         float* __restrict__ ws) {
    __shared__ float bt[184];   // bin table: f*40+k*8 {cw,iw,ch,h,dl,dr,d,s2}; bnd 160; scal 176
    const int t = threadIdx.x;
    if (t < 12) {
        const int f = t & 3;
        const int role = t >> 2;
        const float* p = layers + f * (3 * KBINS - 1);
        if (role == 0) {
            float e[KBINS];
            float m = p[0];
            for (int i = 1; i < KBINS; ++i) m = fmaxf(m, p[i]);
            float s = 0.f;
            for (int i = 0; i < KBINS; ++i) { e[i] = expf(p[i] - m); s += e[i]; }
            float cs = 0.f;
            for (int k = 0; k < KBINS; ++k) {
                float Wk = (e[k] / s) * (2.f * BV);
                bt[f * 40 + k * 8 + 0] = cs - BV;
                bt[f * 40 + k * 8 + 1] = 1.f / Wk;
                cs += Wk;
                if (k < KBINS - 1) bt[160 + f * 4 + k] = cs - BV;
            }
        } else if (role == 1) {
            float e[KBINS];
            float m = p[KBINS];
            for (int i = 1; i < KBINS; ++i) m = fmaxf(m, p[KBINS + i]);
            float s = 0.f;
            for (int i = 0; i < KBINS; ++i) { e[i] = expf(p[KBINS + i] - m); s += e[i]; }
            float cs = 0.f;
            for (int k = 0; k < KBINS; ++k) {
                float Hk = (e[k] / s) * (2.f * BV);
                bt[f * 40 + k * 8 + 2] = cs - BV;
                bt[f * 40 + k * 8 + 3] = Hk;
                cs += Hk;
            }
        } else {
            float dv[KBINS + 1];
            dv[0] = 1.f;
            dv[KBINS] = 1.f;
            for (int i = 0; i < KBINS - 1; ++i)
                dv[i + 1] = 2.f / (1.f + expf(-p[2 * KBINS + i]));
            for (int k = 0; k < KBINS; ++k) {
                bt[f * 40 + k * 8 + 4] = dv[k];
                bt[f * 40 + k * 8 + 5] = dv[k + 1];
            }
        }
    }
    if (t == 12) {
        bt[176] = ip[0];
        bt[177] = -0.5f * logf(2.f * (float)M_PI) - 0.5f * ip[1];
        bt[178] = expf(-ip[1]);
    }
    __syncthreads();
    if (t < 32) {
        const int f = t >> 3, k = t & 7;
        if (k < KBINS) {
            float* b = &bt[f * 40 + k * 8];
            float d = b[3] * b[1];
            b[6] = d;
            b[7] = fmaf(-2.f, d, b[4] + b[5]);
        }
    }
    __syncthreads();
    if (t < 100) {
        const int f = t / 25, c = t % 25;
        const int k0 = c / 5, k1 = c % 5;
        const float* b0 = &bt[f * 40 + k0 * 8];
        const float* b1 = &bt[f * 40 + k1 * 8];
        float* o = ws + f * 500 + c * 20;
#pragma unroll
        for (int w = 0; w < 8; ++w) {
            o[2 * w]     = b0[w];
            o[2 * w + 1] = b1[w];
        }
        o[16] = 0.f; o[17] = 0.f; o[18] = 0.f; o[19] = 0.f;
    }
    if (t >= 100 && t < 116)
        ws[BND_OFF + (t - 100)] = bt[160 + (t - 100)];
    if (t == 116) {
        ws[SCAL_OFF + 0] = bt[176];
        ws[SCAL_OFF + 1] = bt[177];
        ws[SCAL_OFF + 2] = bt[178];
        ws[SCAL_OFF + 3] = 0.f;
    }
}

__global__ __launch_bounds__(256, 4) void nsf_main(
    const float* __restrict__ xin,
    const float* __restrict__ ws,
    float* __restrict__ out,
    unsigned int n) {
    __shared__ __align__(16) float tbl[CT_V4 * 4];
    const int t = threadIdx.x;
#pragma unroll
    for (int i = t; i < CT_V4; i += 256)
        reinterpret_cast<f32x4*>(tbl)[i] = reinterpret_cast<const f32x4*>(ws)[i];
    __syncthreads();

    const float mu = tbl[SCAL_OFF + 0];
    const float c0 = tbl[SCAL_OFF + 1];
    const float ivar = tbl[SCAL_OFF + 2];

    const unsigned int n4 = n >> 2;
    const unsigned int q = blockIdx.x * 256u + (unsigned int)threadIdx.x;

    if (q < n4) {
        const f32x4 xv = reinterpret_cast<const f32x4*>(xin)[q];
        f32x2 xc2[2];
        f32x2 pa2[2], pb2[2];
        xc2[0] = (f32x2){__builtin_amdgcn_fmed3f(xv.x, -BV, BV),
                         __builtin_amdgcn_fmed3f(xv.y, -BV, BV)};
        xc2[1] = (f32x2){__builtin_amdgcn_fmed3f(xv.z, -BV, BV),
                         __builtin_amdgcn_fmed3f(xv.w, -BV, BV)};
        pa2[0] = (f32x2){1.f, 1.f};
        pa2[1] = (f32x2){1.f, 1.f};
        pb2[0] = (f32x2){1.f, 1.f};
        pb2[1] = (f32x2){1.f, 1.f};

#pragma unroll
        for (int f = 0; f < NF; ++f) {
            const f32x4 bb = *reinterpret_cast<const f32x4*>(&tbl[BND_OFF + f * 4]);
            f32x4 r0[2], r1[2], r2[2], r3[2];
#pragma unroll
            for (int pr = 0; pr < 2; ++pr) {
                const float xs0 = xc2[pr].x;
                const float xs1 = xc2[pr].y;
                int k0 = (xs0 >= bb.x) + (xs0 >= bb.y) + (xs0 >= bb.z) + (xs0 >= bb.w);
                int k1 = (xs1 >= bb.x) + (xs1 >= bb.y) + (xs1 >= bb.z) + (xs1 >= bb.w);
                const float* tt = &tbl[f * 500 + (k0 * 5 + k1) * 20];
                r0[pr] = *reinterpret_cast<const f32x4*>(tt);
                r1[pr] = *reinterpret_cast<const f32x4*>(tt + 4);
                r2[pr] = *reinterpret_cast<const f32x4*>(tt + 8);
                r3[pr] = *reinterpret_cast<const f32x4*>(tt + 12);
            }
#pragma unroll
            for (int pr = 0; pr < 2; ++pr) {
                f32x2 cw = {r0[pr].x, r0[pr].y};
                f32x2 iw = {r0[pr].z, r0[pr].w};
                f32x2 ch = {r1[pr].x, r1[pr].y};
                f32x2 h  = {r1[pr].z, r1[pr].w};
                f32x2 dl = {r2[pr].x, r2[pr].y};
                f32x2 dr = {r2[pr].z, r2[pr].w};
                f32x2 d  = {r3[pr].x, r3[pr].y};
                f32x2 s2 = {r3[pr].z, r3[pr].w};
                f32x2 th = (xc2[pr] - cw) * iw;
                f32x2 omt = 1.f - th;
                f32x2 tomt = th * omt;
                f32x2 th2 = th * th;
                f32x2 den = FMA2(s2, tomt, d);
                f32x2 rden = {__builtin_amdgcn_rcpf(den.x),
                              __builtin_amdgcn_rcpf(den.y)};
                xc2[pr] = FMA2(h * FMA2(d, th2, dl * tomt), rden, ch);
                f32x2 Nn = FMA2(dr, th2, FMA2(d + d, tomt, dl * (omt * omt)));
                f32x2 g = d * rden;
                f32x2 r = (g * g) * Nn;
                if (f == 0) pa2[pr] *= r;
                else if (f == 1) pa2[pr] *= r * SCALE32;
                else if (f == 2) pb2[pr] *= r;
                else pb2[pr] *= r * SCALE32;
            }
        }

        f32x4 v0, v1, v2;
        const f32x2 xv2[2] = {{xv.x, xv.y}, {xv.z, xv.w}};
        const f32x2 ln2v = {LN2F, LN2F};
        const f32x2 n64v = {NEG64LN2F, NEG64LN2F};
        const f32x2 nhiv = {-0.5f * ivar, -0.5f * ivar};
        const f32x2 c0v = {c0, c0};
#pragma unroll
        for (int pr = 0; pr < 2; ++pr) {
            const bool ins0 = (fabsf(xv2[pr].x) <= BV);
            const bool ins1 = (fabsf(xv2[pr].y) <= BV);
            f32x2 l2 = {__log2f(pa2[pr].x) + __log2f(pb2[pr].x),
                        __log2f(pa2[pr].y) + __log2f(pb2[pr].y)};
            f32x2 ldv = FMA2(l2, ln2v, n64v);
            f32x2 xf = {ins0 ? xc2[pr].x : xv2[pr].x,
                        ins1 ? xc2[pr].y : xv2[pr].y};
            f32x2 xm = xf - mu;
            f32x2 xm2 = xm * xm;
            f32x2 lp = FMA2(nhiv, xm2, c0v);
            v0[pr * 2]     = lp.x;
            v0[pr * 2 + 1] = lp.y;
            v1[pr * 2]     = ins0 ? ldv.x : 0.f;
            v1[pr * 2 + 1] = ins1 ? ldv.y : 0.f;
            v2[pr * 2]     = xf.x;
            v2[pr * 2 + 1] = xf.y;
        }
        __builtin_nontemporal_store(v0, reinterpret_cast<f32x4*>(out) + q);
        __builtin_nontemporal_store(v1, reinterpret_cast<f32x4*>(out + n) + q);
        __builtin_nontemporal_store(v2, reinterpret_cast<f32x4*>(out + 2 * n) + q);
    }

    // tail (n not divisible by 4; n = 2^23 here so normally empty)
    const unsigned int rem = n & 3u;
    if (rem && q < rem) {
        unsigned int i = n4 * 4 + q;
        float x0 = xin[i];
        float xc = __builtin_amdgcn_fmed3f(x0, -BV, BV);
        float pa = 1.f, pb = 1.f;
#pragma unroll
        for (int f = 0; f < NF; ++f) {
            const float* bbp = &tbl[BND_OFF + f * 4];
            int k = (xc >= bbp[0]) + (xc >= bbp[1]) + (xc >= bbp[2]) + (xc >= bbp[3]);
            const float* tt = &tbl[f * 500 + (k * 5 + k) * 20];  // diagonal combo
            float cw = tt[0], iw = tt[2], ch = tt[4], h = tt[6];
            float dl = tt[8], dr = tt[10], d = tt[12], s2 = tt[14];
            float th = (xc - cw) * iw;
            float omt = 1.f - th, tomt = th * omt, th2 = th * th;
            float den = fmaf(s2, tomt, d);
            float rden = __builtin_amdgcn_rcpf(den);
            xc = fmaf(h * fmaf(d, th2, dl * tomt), rden, ch);
            float Nn = fmaf(dr, th2, fmaf(d + d, tomt, dl * (omt * omt)));
            float g = d * rden;
            float r = (g * g) * Nn;
            if (f == 0) pa *= r;
            else if (f == 1) pa *= r * SCALE32;
            else if (f == 2) pb *= r;
            else pb *= r * SCALE32;
        }
        const bool ins = (fabsf(x0) <= BV);
        float xf = ins ? xc : x0;
        float l2 = __log2f(pa) + __log2f(pb);
        float ld = ins ? fmaf(l2, LN2F, NEG64LN2F) : 0.f;
        float xm = xf - mu;
        out[i] = fmaf(-0.5f * ivar, xm * xm, c0);
        out[n + i] = ld;
        out[2 * n + i] = xf;
    }
}

extern "C" void kernel_launch(void* const* d_in, const int* in_sizes, int n_in,
                              void* d_out, int out_size, void* d_ws, size_t ws_size,
                              hipStream_t stream) {
    const float* x = (const float*)d_in[0];
    const float* layers = (const float*)d_in[1];
    const float* ip = (const float*)d_in[2];
    float* ws = (float*)d_ws;
    float* out = (float*)d_out;
    const unsigned int n = (unsigned int)in_sizes[0];

    hipLaunchKernelGGL(nsf_prep, dim3(1), dim3(128), 0, stream, layers, ip, ws);

    const unsigned int n4 = (n + 3u) >> 2;
    unsigned int blocks = (n4 + 255u) / 256u;
    if (blocks < 1u) blocks = 1u;
    hipLaunchKernelGGL(nsf_main, dim3(blocks), dim3(256), 0, stream, x, ws, out, n);
}

// Round 18
// 35.558 us; speedup vs baseline: 1.7992x; 1.0157x over previous
//
#include <hip/hip_runtime.h>
#include <hip/hip_bf16.h>
#include <math.h>

#define KBINS 5
#define NF 4
#define BV 3.0f

typedef float f32x4 __attribute__((ext_vector_type(4)));
typedef float f32x2 __attribute__((ext_vector_type(2)));
#define FMA2(a, b, c) __builtin_elementwise_fma((f32x2)(a), (f32x2)(b), (f32x2)(c))

// ws/tbl layout (floats):
//   [0,2000):    combo tables: f*500 + (k0*5+k1)*20 +
//                {cw0,cw1, iw0,iw1, ch0,ch1, h0,h1, dl0,dl1, dr0,dr1, d0,d1, s20,s21, pad*4}
//   [2000,2016): interior boundaries: f*4 + j
//   [2016,2019): mu, c0, ivar  (2019 pad)
#define BND_OFF 2000
#define SCAL_OFF 2016
#define CT_V4 505            // 2020 floats / 4
#define SCALE32 4294967296.0f
#define LN2F 0.693147180559945f
#define NEG64LN2F -44.3614195558364798f

__global__ void nsf_prep(const float* __restrict__ layers,
                         const float* __restrict__ ip,
                         float* __restrict__ ws) {
    __shared__ float bt[184];   // bin table: f*40+k*8 {cw,iw,ch,h,dl,dr,d,s2}; bnd 160; scal 176
    const int t = threadIdx.x;
    if (t < 12) {
        const int f = t & 3;
        const int role = t >> 2;
        const float* p = layers + f * (3 * KBINS - 1);
        if (role == 0) {
            float e[KBINS];
            float m = p[0];
            for (int i = 1; i < KBINS; ++i) m = fmaxf(m, p[i]);
            float s = 0.f;
            for (int i = 0; i < KBINS; ++i) { e[i] = expf(p[i] - m); s += e[i]; }
            float cs = 0.f;
            for (int k = 0; k < KBINS; ++k) {
                float Wk = (e[k] / s) * (2.f * BV);
                bt[f * 40 + k * 8 + 0] = cs - BV;
                bt[f * 40 + k * 8 + 1] = 1.f / Wk;
                cs += Wk;
                if (k < KBINS - 1) bt[160 + f * 4 + k] = cs - BV;
            }
        } else if (role == 1) {
            float e[KBINS];
            float m = p[KBINS];
            for (int i = 1; i < KBINS; ++i) m = fmaxf(m, p[KBINS + i]);
            float s = 0.f;
            for (int i = 0; i < KBINS; ++i) { e[i] = expf(p[KBINS + i] - m); s += e[i]; }
            float cs = 0.f;
            for (int k = 0; k < KBINS; ++k) {
                float Hk = (e[k] / s) * (2.f * BV);
                bt[f * 40 + k * 8 + 2] = cs - BV;
                bt[f * 40 + k * 8 + 3] = Hk;
                cs += Hk;
            }
        } else {
            float dv[KBINS + 1];
            dv[0] = 1.f;
            dv[KBINS] = 1.f;
            for (int i = 0; i < KBINS - 1; ++i)
                dv[i + 1] = 2.f / (1.f + expf(-p[2 * KBINS + i]));
            for (int k = 0; k < KBINS; ++k) {
                bt[f * 40 + k * 8 + 4] = dv[k];
                bt[f * 40 + k * 8 + 5] = dv[k + 1];
            }
        }
    }
    if (t == 12) {
        bt[176] = ip[0];
        bt[177] = -0.5f * logf(2.f * (float)M_PI) - 0.5f * ip[1];
        bt[178] = expf(-ip[1]);
    }
    __syncthreads();
    if (t < 32) {
        const int f = t >> 3, k = t & 7;
        if (k < KBINS) {
            float* b = &bt[f * 40 + k * 8];
            float d = b[3] * b[1];
            b[6] = d;
            b[7] = fmaf(-2.f, d, b[4] + b[5]);
        }
    }
    __syncthreads();
    if (t < 100) {
        const int f = t / 25, c = t % 25;
        const int k0 = c / 5, k1 = c % 5;
        const float* b0 = &bt[f * 40 + k0 * 8];
        const float* b1 = &bt[f * 40 + k1 * 8];
        float* o = ws + f * 500 + c * 20;
#pragma unroll
        for (int w = 0; w < 8; ++w) {
            o[2 * w]     = b0[w];
            o[2 * w + 1] = b1[w];
        }
        o[16] = 0.f; o[17] = 0.f; o[18] = 0.f; o[19] = 0.f;
    }
    if (t >= 100 && t < 116)
        ws[BND_OFF + (t - 100)] = bt[160 + (t - 100)];
    if (t == 116) {
        ws[SCAL_OFF + 0] = bt[176];
        ws[SCAL_OFF + 1] = bt[177];
        ws[SCAL_OFF + 2] = bt[178];
        ws[SCAL_OFF + 3] = 0.f;
    }
}

__global__ __launch_bounds__(256, 4) void nsf_main(
    const float* __restrict__ xin,
    const float* __restrict__ ws,
    float* __restrict__ out,
    unsigned int n) {
    __shared__ __align__(16) float tbl[CT_V4 * 4];
    const int t = threadIdx.x;
#pragma unroll
    for (int i = t; i < CT_V4; i += 256)
        reinterpret_cast<f32x4*>(tbl)[i] = reinterpret_cast<const f32x4*>(ws)[i];
    __syncthreads();

    const float mu = tbl[SCAL_OFF + 0];
    const float c0 = tbl[SCAL_OFF + 1];
    const float ivar = tbl[SCAL_OFF + 2];

    const unsigned int n4 = n >> 2;
    const unsigned int q = blockIdx.x * 256u + (unsigned int)threadIdx.x;

    if (q < n4) {
        const f32x4 xv = reinterpret_cast<const f32x4*>(xin)[q];
        f32x2 xc2[2];
        f32x2 pa2[2], pb2[2];
        xc2[0] = (f32x2){__builtin_amdgcn_fmed3f(xv.x, -BV, BV),
                         __builtin_amdgcn_fmed3f(xv.y, -BV, BV)};
        xc2[1] = (f32x2){__builtin_amdgcn_fmed3f(xv.z, -BV, BV),
                         __builtin_amdgcn_fmed3f(xv.w, -BV, BV)};

#pragma unroll
        for (int f = 0; f < NF; ++f) {
            const f32x4 bb = *reinterpret_cast<const f32x4*>(&tbl[BND_OFF + f * 4]);
            f32x4 r0[2], r1[2], r2[2], r3[2];
#pragma unroll
            for (int pr = 0; pr < 2; ++pr) {
                const float xs0 = xc2[pr].x;
                const float xs1 = xc2[pr].y;
                int k0 = (xs0 >= bb.x) + (xs0 >= bb.y) + (xs0 >= bb.z) + (xs0 >= bb.w);
                int k1 = (xs1 >= bb.x) + (xs1 >= bb.y) + (xs1 >= bb.z) + (xs1 >= bb.w);
                const float* tt = &tbl[f * 500 + (k0 * 5 + k1) * 20];
                r0[pr] = *reinterpret_cast<const f32x4*>(tt);
                r1[pr] = *reinterpret_cast<const f32x4*>(tt + 4);
                r2[pr] = *reinterpret_cast<const f32x4*>(tt + 8);
                r3[pr] = *reinterpret_cast<const f32x4*>(tt + 12);
            }
#pragma unroll
            for (int pr = 0; pr < 2; ++pr) {
                f32x2 cw = {r0[pr].x, r0[pr].y};
                f32x2 iw = {r0[pr].z, r0[pr].w};
                f32x2 ch = {r1[pr].x, r1[pr].y};
                f32x2 h  = {r1[pr].z, r1[pr].w};
                f32x2 dl = {r2[pr].x, r2[pr].y};
                f32x2 dr = {r2[pr].z, r2[pr].w};
                f32x2 d  = {r3[pr].x, r3[pr].y};
                f32x2 s2 = {r3[pr].z, r3[pr].w};
                f32x2 th = (xc2[pr] - cw) * iw;
                f32x2 omt = 1.f - th;
                f32x2 tomt = th * omt;
                f32x2 th2 = th * th;
                f32x2 den = FMA2(s2, tomt, d);
                f32x2 rden = {__builtin_amdgcn_rcpf(den.x),
                              __builtin_amdgcn_rcpf(den.y)};
                xc2[pr] = FMA2(h * FMA2(d, th2, dl * tomt), rden, ch);
                f32x2 Nn = FMA2(dr, th2, FMA2(d + d, tomt, dl * (omt * omt)));
                f32x2 g = d * rden;
                f32x2 r = (g * g) * Nn;
                if (f == 0) pa2[pr] = r;
                else if (f == 1) pa2[pr] *= r * SCALE32;
                else if (f == 2) pb2[pr] = r;
                else pb2[pr] *= r * SCALE32;
            }
        }

        f32x4 v0, v1, v2;
        const f32x2 xv2[2] = {{xv.x, xv.y}, {xv.z, xv.w}};
        const f32x2 ln2v = {LN2F, LN2F};
        const f32x2 n64v = {NEG64LN2F, NEG64LN2F};
        const f32x2 nhiv = {-0.5f * ivar, -0.5f * ivar};
        const f32x2 c0v = {c0, c0};
#pragma unroll
        for (int pr = 0; pr < 2; ++pr) {
            const bool ins0 = (fabsf(xv2[pr].x) <= BV);
            const bool ins1 = (fabsf(xv2[pr].y) <= BV);
            f32x2 l2 = {__log2f(pa2[pr].x) + __log2f(pb2[pr].x),
                        __log2f(pa2[pr].y) + __log2f(pb2[pr].y)};
            f32x2 ldv = FMA2(l2, ln2v, n64v);
            f32x2 xf = {ins0 ? xc2[pr].x : xv2[pr].x,
                        ins1 ? xc2[pr].y : xv2[pr].y};
            f32x2 xm = xf - mu;
            f32x2 xm2 = xm * xm;
            f32x2 lp = FMA2(nhiv, xm2, c0v);
            v0[pr * 2]     = lp.x;
            v0[pr * 2 + 1] = lp.y;
            v1[pr * 2]     = ins0 ? ldv.x : 0.f;
            v1[pr * 2 + 1] = ins1 ? ldv.y : 0.f;
            v2[pr * 2]     = xf.x;
            v2[pr * 2 + 1] = xf.y;
        }
        reinterpret_cast<f32x4*>(out)[q] = v0;
        reinterpret_cast<f32x4*>(out + n)[q] = v1;
        reinterpret_cast<f32x4*>(out + 2 * n)[q] = v2;
    }

    // tail (n not divisible by 4; n = 2^23 here so normally empty)
    const unsigned int rem = n & 3u;
    if (rem && q < rem) {
        unsigned int i = n4 * 4 + q;
        float x0 = xin[i];
        float xc = __builtin_amdgcn_fmed3f(x0, -BV, BV);
        float pa = 1.f, pb = 1.f;
#pragma unroll
        for (int f = 0; f < NF; ++f) {
            const float* bbp = &tbl[BND_OFF + f * 4];
            int k = (xc >= bbp[0]) + (xc >= bbp[1]) + (xc >= bbp[2]) + (xc >= bbp[3]);
            const float* tt = &tbl[f * 500 + (k * 5 + k) * 20];  // diagonal combo
            float cw = tt[0], iw = tt[2], ch = tt[4], h = tt[6];
            float dl = tt[8], dr = tt[10], d = tt[12], s2 = tt[14];
            float th = (xc - cw) * iw;
            float omt = 1.f - th, tomt = th * omt, th2 = th * th;
            float den = fmaf(s2, tomt, d);
            float rden = __builtin_amdgcn_rcpf(den);
            xc = fmaf(h * fmaf(d, th2, dl * tomt), rden, ch);
            float Nn = fmaf(dr, th2, fmaf(d + d, tomt, dl * (omt * omt)));
            float g = d * rden;
            float r = (g * g) * Nn;
            if (f == 0) pa = r;
            else if (f == 1) pa *= r * SCALE32;
            else if (f == 2) pb = r;
            else pb *= r * SCALE32;
        }
        const bool ins = (fabsf(x0) <= BV);
        float xf = ins ? xc : x0;
        float l2 = __log2f(pa) + __log2f(pb);
        float ld = ins ? fmaf(l2, LN2F, NEG64LN2F) : 0.f;
        float xm = xf - mu;
        out[i] = fmaf(-0.5f * ivar, xm * xm, c0);
        out[n + i] = ld;
        out[2 * n + i] = xf;
    }
}

extern "C" void kernel_launch(void* const* d_in, const int* in_sizes, int n_in,
                              void* d_out, int out_size, void* d_ws, size_t ws_size,
                              hipStream_t stream) {
    const float* x = (const float*)d_in[0];
    const float* layers = (const float*)d_in[1];
    const float* ip = (const float*)d_in[2];
    float* ws = (float*)d_ws;
    float* out = (float*)d_out;
    const unsigned int n = (unsigned int)in_sizes[0];

    hipLaunchKernelGGL(nsf_prep, dim3(1), dim3(128), 0, stream, layers, ip, ws);

    const unsigned int n4 = (n + 3u) >> 2;
    unsigned int blocks = (n4 + 255u) / 256u;
    if (blocks < 1u) blocks = 1u;
    hipLaunchKernelGGL(nsf_main, dim3(blocks), dim3(256), 0, stream, x, ws, out, n);
}